// Round 1
// baseline (74.243 us; speedup 1.0000x reference)
//
#include <hip/hip_runtime.h>
#include <hip/hip_bf16.h>

// Problem: B=4, S=4096, D=64, fp32 in/out.
// out[b,i,d] = sum_j (q[b,i,:]·k[b,j,:]) * v[b,j,d]  ==  Q @ (K^T @ V)  (no softmax)
// Factored: M[b] = K^T V (64x64 per batch), out = Q @ M. 268 MFLOP, ~16MiB traffic.

#define BATCH 4
#define SEQ   4096
#define DIM   64
#define NCH   64      // chunks per batch (k1)
#define CHUNK 64      // rows per chunk

typedef float f4  __attribute__((ext_vector_type(4)));
typedef short bf16x8 __attribute__((ext_vector_type(8)));
typedef float f32x4  __attribute__((ext_vector_type(4)));

__device__ inline unsigned short f2bf(float f) {
    union { float f; unsigned u; } v; v.f = f;
    unsigned r = (v.u + 0x7fffu + ((v.u >> 16) & 1u)) >> 16;  // RTN-even
    return (unsigned short)r;
}

// ---------------- k1: partial M = K_chunk^T @ V_chunk --------------------
// grid 256 = batch*64 + chunk; block 256. LDS 32KB. Each thread: 4x4 tile of 64x64 M.
__global__ __launch_bounds__(256) void k1_partial(const float* __restrict__ K,
                                                  const float* __restrict__ V,
                                                  float* __restrict__ part) {
    __shared__ f4 Ks[1024];   // 64 rows x 16 float4
    __shared__ f4 Vs[1024];
    const int bx = blockIdx.x;        // b*64 + ch; flat row offset = bx*64 rows
    const int t  = threadIdx.x;
    const f4* Kg = (const f4*)(K + (size_t)bx * (CHUNK * DIM));
    const f4* Vg = (const f4*)(V + (size_t)bx * (CHUNK * DIM));
#pragma unroll
    for (int i = 0; i < 4; ++i) {
        Ks[t + 256 * i] = Kg[t + 256 * i];
        Vs[t + 256 * i] = Vg[t + 256 * i];
    }
    __syncthreads();
    const int rg = t >> 4;     // 0..15 -> rows r0 = rg*4 (d1 dim)
    const int cg = t & 15;     // 0..15 -> cols c0 = cg*4 (d2 dim)
    f4 acc0 = 0.f, acc1 = 0.f, acc2 = 0.f, acc3 = 0.f;
#pragma unroll 8
    for (int j = 0; j < CHUNK; ++j) {
        f4 a = Ks[j * 16 + rg];   // K[j][r0..r0+3]
        f4 v = Vs[j * 16 + cg];   // V[j][c0..c0+3]
        acc0 += v * a.x;
        acc1 += v * a.y;
        acc2 += v * a.z;
        acc3 += v * a.w;
    }
    f4* P = (f4*)part + (size_t)bx * 1024;   // 64x64 partial, row-major, as float4
    P[(rg * 4 + 0) * 16 + cg] = acc0;
    P[(rg * 4 + 1) * 16 + cg] = acc1;
    P[(rg * 4 + 2) * 16 + cg] = acc2;
    P[(rg * 4 + 3) * 16 + cg] = acc3;
}

// ---------------- k2: reduce partials -> M, emit bf16 in MFMA B-frag order ----
// grid 64 x 256 threads = 16384 = 4 batches * 4096 elements of M.
// B-frag layout for mfma_f32_16x16x32_bf16: lane holds B[k=quad*8+j][n=lane&15],
// per (ct,ks) tile: k = ks*32 + quad*8 + j, n = ct*16 + m.
// MB index = ((b*8 + ct*2 + ks)*64 + quad*16 + m)*8 + j   (bf16)
__global__ __launch_bounds__(256) void k2_reduce(const float* __restrict__ part,
                                                 unsigned short* __restrict__ MB) {
    const int tg = blockIdx.x * 256 + threadIdx.x;   // 0..16383
    const int b = tg >> 12;
    const int e = tg & 4095;                          // d'*64 + c
    float s = 0.f;
#pragma unroll 8
    for (int p = 0; p < NCH; ++p)
        s += part[((size_t)(b * NCH + p)) * 4096 + e];
    const int dp = e >> 6;      // k index (d')
    const int c  = e & 63;      // n index
    const int ct = c >> 4, m = c & 15;
    const int ks = dp >> 5, quad = (dp >> 3) & 3, j = dp & 7;
    const int idx = (((b * 8 + ct * 2 + ks) * 64) + quad * 16 + m) * 8 + j;
    MB[idx] = f2bf(s);
}

// ---------------- k3: out = Q @ M via MFMA, zero LDS ---------------------
// grid 256 (b*64 + rowblock of 64), block 256 = 4 waves x 16 rows each.
__global__ __launch_bounds__(256) void k3_qm(const float* __restrict__ Q,
                                             const unsigned short* __restrict__ MB,
                                             float* __restrict__ out) {
    const int bx = blockIdx.x;
    const int t  = threadIdx.x;
    const int wave = t >> 6, lane = t & 63;
    const int m = lane & 15, quad = lane >> 4;
    const int b = bx >> 6;
    const int row0 = (bx & 63) * 64 + wave * 16;     // row tile within batch

    // A-fragments: Q[row0+m][ks*32 + quad*8 .. +8] -> bf16x8, straight from global
    const float* qrow = Q + ((size_t)b * SEQ + row0 + m) * DIM;
    bf16x8 afrag[2];
#pragma unroll
    for (int ks = 0; ks < 2; ++ks) {
        const f4* qp = (const f4*)(qrow + ks * 32 + quad * 8);
        f4 q1 = qp[0], q2 = qp[1];
        bf16x8 a;
        a[0] = (short)f2bf(q1.x); a[1] = (short)f2bf(q1.y);
        a[2] = (short)f2bf(q1.z); a[3] = (short)f2bf(q1.w);
        a[4] = (short)f2bf(q2.x); a[5] = (short)f2bf(q2.y);
        a[6] = (short)f2bf(q2.z); a[7] = (short)f2bf(q2.w);
        afrag[ks] = a;
    }

    const bf16x8* MBv = (const bf16x8*)MB + (size_t)b * 8 * 64;
    f32x4 acc[4];
#pragma unroll
    for (int ct = 0; ct < 4; ++ct) { acc[ct] = (f32x4)0.f; }
#pragma unroll
    for (int ct = 0; ct < 4; ++ct) {
#pragma unroll
        for (int ks = 0; ks < 2; ++ks) {
            bf16x8 bfrag = MBv[(ct * 2 + ks) * 64 + lane];
            acc[ct] = __builtin_amdgcn_mfma_f32_16x16x32_bf16(afrag[ks], bfrag, acc[ct], 0, 0, 0);
        }
    }

    // C/D layout: col = ct*16 + (lane&15), row = quad*4 + reg
    float* orow = out + ((size_t)b * SEQ + row0) * DIM;
#pragma unroll
    for (int ct = 0; ct < 4; ++ct) {
#pragma unroll
        for (int r = 0; r < 4; ++r) {
            orow[(quad * 4 + r) * DIM + ct * 16 + m] = acc[ct][r];
        }
    }
}

extern "C" void kernel_launch(void* const* d_in, const int* in_sizes, int n_in,
                              void* d_out, int out_size, void* d_ws, size_t ws_size,
                              hipStream_t stream) {
    const float* q = (const float*)d_in[0];
    const float* k = (const float*)d_in[1];
    const float* v = (const float*)d_in[2];
    float* out = (float*)d_out;

    float* part = (float*)d_ws;                                      // 4 MiB
    unsigned short* MB = (unsigned short*)((char*)d_ws + (size_t)4 * 1024 * 1024); // 32 KiB

    k1_partial<<<BATCH * NCH, 256, 0, stream>>>(k, v, part);
    k2_reduce<<<64, 256, 0, stream>>>(part, MB);
    k3_qm<<<BATCH * NCH, 256, 0, stream>>>(q, MB, out);
}